// Round 7
// baseline (2740.770 us; speedup 1.0000x reference)
//
#include <hip/hip_runtime.h>
#include <math.h>

#define N_NODES 50000
#define D 128
#define NE 800000
#define BNODES 64              // nodes per bucket (dst >> 6)
#define NBUCK 782              // ceil(N_NODES / 64)
#define CAP 1536               // records per bucket (mean 1024, sigma 32 -> 16 sigma)
#define ACC_PITCH 132          // f32 pitch, 16B-aligned rows, bank-spread
#define EPB 4096               // edges per partition block
#define PBLK 196               // ceil(NE / EPB)
#define F2B_BLKS 6250          // N*D/4 / 256
#define WPREP_BLKS 384         // 2*12*128*32 / 256
#define MEGA_LDS (2 * BNODES * ACC_PITCH * 4 + 2 * BNODES * 4)   // 68096 B

typedef unsigned int uint;
typedef unsigned short ushort;

using bf16x8 = __attribute__((ext_vector_type(8))) short;
using f32x4  = __attribute__((ext_vector_type(4))) float;

// ---- bf16 helpers (bit-level, RN-even) ----
__device__ __forceinline__ float bflo(uint w) {
    union { uint u; float f; } c; c.u = w << 16; return c.f;
}
__device__ __forceinline__ float bfhi(uint w) {
    union { uint u; float f; } c; c.u = w & 0xffff0000u; return c.f;
}
__device__ __forceinline__ uint fp2bf_rn(float f) {
    union { float f; uint u; } c; c.f = f;
    return (c.u + 0x7fffu + ((c.u >> 16) & 1u)) >> 16;
}

// ---------------------------------------------------------------------------
// build: [0, 2*PBLK) edge partition into bucket record runs;
//        [2*PBLK, +F2B_BLKS) x -> bf16;  then W pre-pack.
// rec = src | (dst&63)<<17.  After this kernel bcur[b] = bucket record count.
// ---------------------------------------------------------------------------
__global__ __launch_bounds__(256) void build_kernel(
    const float4* __restrict__ x4, uint2* __restrict__ featb2,
    const float* __restrict__ Wl, const float* __restrict__ Wr,
    ushort* __restrict__ Wpack,
    const int* __restrict__ srcA, const int* __restrict__ dstA,
    const int* __restrict__ srcB, const int* __restrict__ dstB,
    int* __restrict__ bcurA, int* __restrict__ bcurB,
    uint* __restrict__ ebufA, uint* __restrict__ ebufB) {
    const int blk = blockIdx.x;
    const int t   = threadIdx.x;
    if (blk < 2 * PBLK) {
        __shared__ int h[NBUCK];
        __shared__ int base[NBUCK];
        const int typ = blk >= PBLK;
        const int* src = typ ? srcB : srcA;
        const int* dst = typ ? dstB : dstA;
        int* bc        = typ ? bcurB : bcurA;
        uint* ebuf     = typ ? ebufB : ebufA;
        const int e0 = (blk - (typ ? PBLK : 0)) * EPB;
        for (int j = t; j < NBUCK; j += 256) h[j] = 0;
        __syncthreads();
#pragma unroll
        for (int i = 0; i < EPB / 256; ++i) {
            const int e = e0 + t + i * 256;
            if (e < NE) atomicAdd(&h[dst[e] >> 6], 1);
        }
        __syncthreads();
        for (int j = t; j < NBUCK; j += 256) {
            const int c = h[j];
            base[j] = c ? atomicAdd(&bc[j], c) : 0;
            h[j] = 0;                    // reuse as local cursor
        }
        __syncthreads();
#pragma unroll
        for (int i = 0; i < EPB / 256; ++i) {
            const int e = e0 + t + i * 256;
            if (e < NE) {
                const int d  = dst[e];
                const int bk = d >> 6;
                const int pos = atomicAdd(&h[bk], 1);
                const int off = base[bk] + pos;
                if (off < CAP)
                    ebuf[(size_t)bk * CAP + off] = (uint)src[e] | ((uint)(d & 63) << 17);
            }
        }
    } else if (blk < 2 * PBLK + F2B_BLKS) {
        const int i = (blk - 2 * PBLK) * 256 + t;
        float4 v = x4[i];
        uint2 o;
        o.x = fp2bf_rn(v.x) | (fp2bf_rn(v.y) << 16);
        o.y = fp2bf_rn(v.z) | (fp2bf_rn(v.w) << 16);
        featb2[i] = o;
    } else {
        const int i   = (blk - 2 * PBLK - F2B_BLKS) * 256 + t;  // [2][12][128][32]
        const int l   = i / 49152;
        const int rem = i % 49152;
        const int ks  = rem / 4096;
        const int n   = (rem % 4096) / 32;
        const int kk  = rem % 32;
        const int r   = ks * 32 + kk;
        float v;
        if (r < 128)       v = Wl[(((size_t)l * 2 + 0) * 128 + r) * 128 + n];
        else if (r < 256)  v = Wl[(((size_t)l * 2 + 1) * 128 + (r - 128)) * 128 + n];
        else               v = Wr[(((size_t)l * 2 + 0) * 128 + (r - 256)) * 128 + n]
                             + Wr[(((size_t)l * 2 + 1) * 128 + (r - 256)) * 128 + n];
        Wpack[i] = (ushort)fp2bf_rn(v);
    }
}

// ---------------------------------------------------------------------------
// mega: per 64-node bucket: gather+LDS-f32-accumulate both types' means,
// then in-kernel 64x128 MFMA GEMM over K=384 = [meanA|meanB|self].
//   out[i,:] = act( meanA@W0 + meanB@W1 + self@(Wr0+Wr1) + b0+b1 )
// 1024 threads = 16 waves; gather: 64 clusters x 16 lanes (16B/lane);
// GEMM: wave w -> Mtile w>>2, Ntiles (w&3)*2, +1.
// ---------------------------------------------------------------------------
__global__ __launch_bounds__(1024, 8) void mega_kernel(
    const uint4* __restrict__ feat,      // layer input, bf16 [N][16]
    const uint* __restrict__ ebufA, const uint* __restrict__ ebufB,
    const int* __restrict__ bcntA, const int* __restrict__ bcntB,
    const ushort* __restrict__ Wpack,    // [12][128][32] bf16 for this layer
    const float* __restrict__ bias0, const float* __restrict__ bias1,
    float* __restrict__ outf, ushort* __restrict__ outb, int act) {

    extern __shared__ float smem[];      // [2][BNODES][ACC_PITCH] f32 + cnt[2][BNODES]
    int* cnt = (int*)(smem + 2 * BNODES * ACC_PITCH);
    const int b = blockIdx.x;
    const int t = threadIdx.x;

    for (int i = t; i < 2 * BNODES * ACC_PITCH; i += 1024) smem[i] = 0.f;
    if (t < 2 * BNODES) cnt[t] = 0;
    __syncthreads();

    // ---- gather + accumulate (both types) ----
    const int cl = t >> 4, lane = t & 15;
#define ACC8(ap, v) { \
    atomicAdd((ap) + 0, bflo(v.x)); atomicAdd((ap) + 1, bfhi(v.x)); \
    atomicAdd((ap) + 2, bflo(v.y)); atomicAdd((ap) + 3, bfhi(v.y)); \
    atomicAdd((ap) + 4, bflo(v.z)); atomicAdd((ap) + 5, bfhi(v.z)); \
    atomicAdd((ap) + 6, bflo(v.w)); atomicAdd((ap) + 7, bfhi(v.w)); }
    for (int typ = 0; typ < 2; ++typ) {
        const uint* ebuf = (typ ? ebufB : ebufA) + (size_t)b * CAP;
        int count = (typ ? bcntB : bcntA)[b];
        if (count > CAP) count = CAP;
        float* acc = smem + typ * BNODES * ACC_PITCH;
        int* cn = cnt + typ * BNODES;
        int e = cl;
        for (; e + 64 < count; e += 128) {
            const uint rec0 = ebuf[e];
            const uint rec1 = ebuf[e + 64];
            const uint4 v0 = feat[(size_t)(rec0 & 0x1FFFFu) * 16 + lane];
            const uint4 v1 = feat[(size_t)(rec1 & 0x1FFFFu) * 16 + lane];
            const int l0 = rec0 >> 17, l1 = rec1 >> 17;
            if (lane == 0) { atomicAdd(&cn[l0], 1); atomicAdd(&cn[l1], 1); }
            float* a0 = acc + l0 * ACC_PITCH + lane * 8;
            ACC8(a0, v0);
            float* a1 = acc + l1 * ACC_PITCH + lane * 8;
            ACC8(a1, v1);
        }
        if (e < count) {
            const uint rec0 = ebuf[e];
            const uint4 v0 = feat[(size_t)(rec0 & 0x1FFFFu) * 16 + lane];
            const int l0 = rec0 >> 17;
            if (lane == 0) atomicAdd(&cn[l0], 1);
            float* a0 = acc + l0 * ACC_PITCH + lane * 8;
            ACC8(a0, v0);
        }
    }
#undef ACC8
    __syncthreads();

    // ---- in-kernel GEMM: 64 rows x 128 cols, K = 12 x 32 ----
    const int wid  = t >> 6, wl = t & 63;
    const int mrow = wl & 15, g = wl >> 4;
    const int mt   = wid >> 2;
    const int nt0  = (wid & 3) * 2;
    const int arow = mt * 16 + mrow;                   // 0..63
    const float invdA = 1.0f / fmaxf((float)cnt[arow], 1.0f);
    const float invdB = 1.0f / fmaxf((float)cnt[BNODES + arow], 1.0f);

    f32x4 acc0 = (f32x4){0.f, 0.f, 0.f, 0.f};
    f32x4 acc1 = (f32x4){0.f, 0.f, 0.f, 0.f};
#pragma unroll
    for (int ks = 0; ks < 12; ++ks) {
        union { uint4 u; bf16x8 v; } av;
        if (ks < 8) {
            const int sel = ks >> 2;                   // 0: meanA, 1: meanB
            const float invd = sel ? invdB : invdA;
            const float* ap = smem + (sel * BNODES + arow) * ACC_PITCH + (ks & 3) * 32 + g * 8;
            const float4 f0 = *(const float4*)ap;
            const float4 f1 = *(const float4*)(ap + 4);
            av.u.x = fp2bf_rn(f0.x * invd) | (fp2bf_rn(f0.y * invd) << 16);
            av.u.y = fp2bf_rn(f0.z * invd) | (fp2bf_rn(f0.w * invd) << 16);
            av.u.z = fp2bf_rn(f1.x * invd) | (fp2bf_rn(f1.y * invd) << 16);
            av.u.w = fp2bf_rn(f1.z * invd) | (fp2bf_rn(f1.w * invd) << 16);
        } else {
            av.u = feat[(size_t)(b * BNODES + arow) * 16 + (ks & 3) * 4 + g];
        }
        const ushort* Wk = Wpack + (size_t)ks * 128 * 32;
        union { uint4 u; bf16x8 v; } bv0, bv1;
        bv0.u = *(const uint4*)(Wk + ((nt0 * 16 + mrow) * 32 + g * 8));
        bv1.u = *(const uint4*)(Wk + (((nt0 + 1) * 16 + mrow) * 32 + g * 8));
        acc0 = __builtin_amdgcn_mfma_f32_16x16x32_bf16(av.v, bv0.v, acc0, 0, 0, 0);
        acc1 = __builtin_amdgcn_mfma_f32_16x16x32_bf16(av.v, bv1.v, acc1, 0, 0, 0);
    }

    // ---- epilogue ----
#pragma unroll
    for (int q = 0; q < 2; ++q) {
        const f32x4 av = q ? acc1 : acc0;
        const int col = (nt0 + q) * 16 + mrow;
        const float bias = bias0[col] + bias1[col];
#pragma unroll
        for (int r = 0; r < 4; ++r) {
            const int row = b * BNODES + mt * 16 + g * 4 + r;
            if (row < N_NODES) {
                const float v = av[r] + bias;
                if (act) outf[(size_t)row * D + col] = 1.0f / (1.0f + expf(-v));
                else     outb[(size_t)row * D + col] = (ushort)fp2bf_rn(v);
            }
        }
    }
}

// ---------------------------------------------------------------------------
extern "C" void kernel_launch(void* const* d_in, const int* in_sizes, int n_in,
                              void* d_out, int out_size, void* d_ws, size_t ws_size,
                              hipStream_t stream) {
    const float* x    = (const float*)d_in[0];
    const int*   ei_a = (const int*)d_in[2];
    const int*   ei_b = (const int*)d_in[3];
    const float* Wl   = (const float*)d_in[4];
    const float* bl   = (const float*)d_in[5];
    const float* Wr   = (const float*)d_in[6];
    float* out = (float*)d_out;

    // ---- workspace (~35.5 MB) ----
    ushort* featb = (ushort*)d_ws;                           // [N][128]
    ushort* feat2 = featb + (size_t)N_NODES * D;             // [N][128]
    uint* ebufA = (uint*)(feat2 + (size_t)N_NODES * D);      // NBUCK*CAP
    uint* ebufB = ebufA + (size_t)NBUCK * CAP;
    int* bcurA  = (int*)(ebufB + (size_t)NBUCK * CAP);       // NBUCK
    int* bcurB  = bcurA + NBUCK;
    ushort* Wpack = (ushort*)(((size_t)(bcurB + NBUCK) + 63) & ~(size_t)63);

    const int* srcA = ei_a;
    const int* dstA = ei_a + NE;
    const int* srcB = ei_b;
    const int* dstB = ei_b + NE;

    hipFuncSetAttribute((const void*)mega_kernel,
                        hipFuncAttributeMaxDynamicSharedMemorySize, MEGA_LDS);

    hipMemsetAsync(bcurA, 0, 2ull * NBUCK * sizeof(int), stream);
    build_kernel<<<2 * PBLK + F2B_BLKS + WPREP_BLKS, 256, 0, stream>>>(
        (const float4*)x, (uint2*)featb, Wl, Wr, Wpack,
        srcA, dstA, srcB, dstB, bcurA, bcurB, ebufA, ebufB);

    mega_kernel<<<NBUCK, 1024, MEGA_LDS, stream>>>(
        (const uint4*)featb, ebufA, ebufB, bcurA, bcurB,
        Wpack, bl + 0 * D, bl + 1 * D, nullptr, feat2, 0);
    mega_kernel<<<NBUCK, 1024, MEGA_LDS, stream>>>(
        (const uint4*)feat2, ebufA, ebufB, bcurA, bcurB,
        Wpack + (size_t)12 * 128 * 32, bl + 2 * D, bl + 3 * D, out, nullptr, 1);
}

// Round 8
// 230.971 us; speedup vs baseline: 11.8663x; 11.8663x over previous
//
#include <hip/hip_runtime.h>
#include <math.h>

#define N_NODES 50000
#define D 128
#define NE 800000
#define BN 64                  // nodes per bucket (dst >> 6)
#define NBUCK 782              // ceil(N_NODES / 64)
#define CAP 1280               // records per bucket (mean 1024, sigma 32 -> 8 sigma)
#define EPB 4096               // edges per partition block
#define PBLK 196               // ceil(NE / EPB)
#define F2B_BLKS 6250          // N*D/4 / 256
#define WPREP_BLKS 384         // 2*12*128*32 / 256
#define MPITCH 68              // uint pitch for LDS mean rows (68 mod 32 = 4)

typedef unsigned int uint;
typedef unsigned short ushort;

using bf16x8 = __attribute__((ext_vector_type(8))) short;
using f32x4  = __attribute__((ext_vector_type(4))) float;

// ---- bf16 helpers (bit-level, RN-even) ----
__device__ __forceinline__ float bflo(uint w) {
    union { uint u; float f; } c; c.u = w << 16; return c.f;
}
__device__ __forceinline__ float bfhi(uint w) {
    union { uint u; float f; } c; c.u = w & 0xffff0000u; return c.f;
}
__device__ __forceinline__ uint fp2bf_rn(float f) {
    union { float f; uint u; } c; c.f = f;
    return (c.u + 0x7fffu + ((c.u >> 16) & 1u)) >> 16;
}

// ---------------------------------------------------------------------------
// build: [0, 2*PBLK) edge partition into bucket record runs;
//        then x -> bf16; then W pre-pack.
// rec = src | (dst&63)<<17.  After this kernel bcur[b] = bucket record count.
// ---------------------------------------------------------------------------
__global__ __launch_bounds__(256) void build_kernel(
    const float4* __restrict__ x4, uint2* __restrict__ featb2,
    const float* __restrict__ Wl, const float* __restrict__ Wr,
    ushort* __restrict__ Wpack,
    const int* __restrict__ srcA, const int* __restrict__ dstA,
    const int* __restrict__ srcB, const int* __restrict__ dstB,
    int* __restrict__ bcurA, int* __restrict__ bcurB,
    uint* __restrict__ ebufA, uint* __restrict__ ebufB) {
    const int blk = blockIdx.x;
    const int t   = threadIdx.x;
    if (blk < 2 * PBLK) {
        __shared__ int h[NBUCK];
        __shared__ int base[NBUCK];
        const int typ = blk >= PBLK;
        const int* src = typ ? srcB : srcA;
        const int* dst = typ ? dstB : dstA;
        int* bc        = typ ? bcurB : bcurA;
        uint* ebuf     = typ ? ebufB : ebufA;
        const int e0 = (blk - (typ ? PBLK : 0)) * EPB;
        for (int j = t; j < NBUCK; j += 256) h[j] = 0;
        __syncthreads();
#pragma unroll
        for (int i = 0; i < EPB / 256; ++i) {
            const int e = e0 + t + i * 256;
            if (e < NE) atomicAdd(&h[dst[e] >> 6], 1);
        }
        __syncthreads();
        for (int j = t; j < NBUCK; j += 256) {
            const int c = h[j];
            base[j] = c ? atomicAdd(&bc[j], c) : 0;
            h[j] = 0;                    // reuse as local cursor
        }
        __syncthreads();
#pragma unroll
        for (int i = 0; i < EPB / 256; ++i) {
            const int e = e0 + t + i * 256;
            if (e < NE) {
                const int d  = dst[e];
                const int bk = d >> 6;
                const int pos = atomicAdd(&h[bk], 1);
                const int off = base[bk] + pos;
                if (off < CAP)
                    ebuf[(size_t)bk * CAP + off] = (uint)src[e] | ((uint)(d & 63) << 17);
            }
        }
    } else if (blk < 2 * PBLK + F2B_BLKS) {
        const int i = (blk - 2 * PBLK) * 256 + t;
        float4 v = x4[i];
        uint2 o;
        o.x = fp2bf_rn(v.x) | (fp2bf_rn(v.y) << 16);
        o.y = fp2bf_rn(v.z) | (fp2bf_rn(v.w) << 16);
        featb2[i] = o;
    } else {
        const int i   = (blk - 2 * PBLK - F2B_BLKS) * 256 + t;  // [2][12][128][32]
        const int l   = i / 49152;
        const int rem = i % 49152;
        const int ks  = rem / 4096;
        const int n   = (rem % 4096) / 32;
        const int kk  = rem % 32;
        const int r   = ks * 32 + kk;
        float v;
        if (r < 128)       v = Wl[(((size_t)l * 2 + 0) * 128 + r) * 128 + n];
        else if (r < 256)  v = Wl[(((size_t)l * 2 + 1) * 128 + (r - 128)) * 128 + n];
        else               v = Wr[(((size_t)l * 2 + 0) * 128 + (r - 256)) * 128 + n]
                             + Wr[(((size_t)l * 2 + 1) * 128 + (r - 256)) * 128 + n];
        Wpack[i] = (ushort)fp2bf_rn(v);
    }
}

// ---------------------------------------------------------------------------
// per-bucket CSR fill: LDS count -> scan(64) -> pbeg/pend + ushort idx
// ---------------------------------------------------------------------------
__global__ __launch_bounds__(256) void csrfill_kernel(
    const uint* __restrict__ ebufA, const int* __restrict__ bcntA,
    int* __restrict__ pbegA, int* __restrict__ pendA, ushort* __restrict__ idxA,
    const uint* __restrict__ ebufB, const int* __restrict__ bcntB,
    int* __restrict__ pbegB, int* __restrict__ pendB, ushort* __restrict__ idxB) {
    __shared__ int cnt[BN];
    __shared__ int lb[BN];
    const int t = threadIdx.x;
    int b = blockIdx.x;
    const int typ = b >= NBUCK;
    if (typ) b -= NBUCK;
    const uint* ebuf = (typ ? ebufB : ebufA) + (size_t)b * CAP;
    int count        = (typ ? bcntB : bcntA)[b];
    if (count > CAP) count = CAP;
    int* pbeg        = typ ? pbegB : pbegA;
    int* pend        = typ ? pendB : pendA;
    ushort* idx      = (typ ? idxB : idxA) + (size_t)b * CAP;

    if (t < BN) cnt[t] = 0;
    __syncthreads();
    for (int e = t; e < count; e += 256)
        atomicAdd(&cnt[ebuf[e] >> 17], 1);
    __syncthreads();
    if (t < BN) lb[t] = cnt[t];
    __syncthreads();
    // inclusive Hillis-Steele scan over 64
    for (int off = 1; off < BN; off <<= 1) {
        int v = 0;
        if (t < BN && t >= off) v = lb[t - off];
        __syncthreads();
        if (t < BN && t >= off) lb[t] += v;
        __syncthreads();
    }
    if (t < BN) {
        const int ex = lb[t] - cnt[t];           // exclusive
        lb[t] = ex;
        const int node = b * BN + t;
        if (node < N_NODES) {
            pbeg[node] = b * CAP + ex;
            pend[node] = b * CAP + ex + cnt[t];
        }
        cnt[t] = 0;                              // reuse as cursor
    }
    __syncthreads();
    for (int e = t; e < count; e += 256) {
        const uint rec = ebuf[e];
        const int local = rec >> 17;
        const int pos = atomicAdd(&cnt[local], 1);
        idx[lb[local] + pos] = (ushort)(rec & 0x1FFFFu);
    }
}

// ---------------------------------------------------------------------------
// fused: per 64-node bucket: register-accumulated mean gather (both types)
// -> LDS bf16 means -> in-kernel 64x128 MFMA GEMM over K=384.
//   out[i,:] = act( meanA@W0 + meanB@W1 + self@(Wr0+Wr1) + b0+b1 )
// 512 threads = 8 waves.  Gather: 32 clusters x 16 lanes, 2 nodes each.
// GEMM: wave w -> Mtile w>>1, N-half (w&1)*4 (4 Ntiles).
// ---------------------------------------------------------------------------
__global__ __launch_bounds__(512, 4) void fused_kernel(
    const uint4* __restrict__ feat,      // layer input, bf16 [N][16]
    const int* __restrict__ pbegA, const int* __restrict__ pendA,
    const ushort* __restrict__ idxA,
    const int* __restrict__ pbegB, const int* __restrict__ pendB,
    const ushort* __restrict__ idxB,
    const ushort* __restrict__ Wpack,    // [12][128][32] bf16 for this layer
    const float* __restrict__ bias0, const float* __restrict__ bias1,
    float* __restrict__ outf, ushort* __restrict__ outb, int act) {

    __shared__ uint mlds[2 * BN * MPITCH];   // bf16 means, [typ][node][row of 128]

    const int b = blockIdx.x;
    const int t = threadIdx.x;
    const int cl = t >> 4, ln = t & 15;

    // ---- gather phase: register accumulation (proven mean2 pattern) ----
    for (int half = 0; half < 2; ++half) {
        const int c    = cl + half * 32;
        const int node = b * BN + c;
        for (int typ = 0; typ < 2; ++typ) {
            const int* pbeg   = typ ? pbegB : pbegA;
            const int* pend   = typ ? pendB : pendA;
            const ushort* idx = typ ? idxB : idxA;
            int beg = 0, fin = 0;
            if (node < N_NODES) { beg = pbeg[node]; fin = pend[node]; }
            float a[8] = {0.f,0.f,0.f,0.f,0.f,0.f,0.f,0.f};
#define ACC(v) { a[0]+=bflo(v.x); a[1]+=bfhi(v.x); a[2]+=bflo(v.y); a[3]+=bfhi(v.y); \
                 a[4]+=bflo(v.z); a[5]+=bfhi(v.z); a[6]+=bflo(v.w); a[7]+=bfhi(v.w); }
            int e = beg;
            for (; e + 4 <= fin; e += 4) {
                uint4 v0 = feat[(size_t)idx[e]     * 16 + ln];
                uint4 v1 = feat[(size_t)idx[e + 1] * 16 + ln];
                uint4 v2 = feat[(size_t)idx[e + 2] * 16 + ln];
                uint4 v3 = feat[(size_t)idx[e + 3] * 16 + ln];
                ACC(v0); ACC(v1); ACC(v2); ACC(v3);
            }
            for (; e < fin; ++e) {
                uint4 v0 = feat[(size_t)idx[e] * 16 + ln];
                ACC(v0);
            }
#undef ACC
            const float invd = 1.0f / fmaxf((float)(fin - beg), 1.0f);
            uint4 o;
            o.x = fp2bf_rn(a[0] * invd) | (fp2bf_rn(a[1] * invd) << 16);
            o.y = fp2bf_rn(a[2] * invd) | (fp2bf_rn(a[3] * invd) << 16);
            o.z = fp2bf_rn(a[4] * invd) | (fp2bf_rn(a[5] * invd) << 16);
            o.w = fp2bf_rn(a[6] * invd) | (fp2bf_rn(a[7] * invd) << 16);
            *reinterpret_cast<uint4*>(&mlds[(typ * BN + c) * MPITCH + ln * 4]) = o;
        }
    }
    __syncthreads();

    // ---- GEMM phase: 64 rows x 128 cols, K = 12 x 32 ----
    const int wid = t >> 6, wl = t & 63;
    const int mrow = wl & 15, g = wl >> 4;
    const int mt   = wid >> 1;             // 0..3
    const int nt0  = (wid & 1) * 4;        // 0 or 4
    const int arow = mt * 16 + mrow;       // 0..63

    f32x4 acc[4];
#pragma unroll
    for (int q = 0; q < 4; ++q) acc[q] = (f32x4){0.f, 0.f, 0.f, 0.f};

#pragma unroll
    for (int ks = 0; ks < 12; ++ks) {
        union { uint4 u; bf16x8 v; } av;
        if (ks < 8) {
            av.u = *reinterpret_cast<const uint4*>(
                &mlds[((ks >> 2) * BN + arow) * MPITCH + (ks & 3) * 16 + g * 4]);
        } else {
            int srow = b * BN + arow;
            if (srow >= N_NODES) srow = N_NODES - 1;
            av.u = feat[(size_t)srow * 16 + (ks & 3) * 4 + g];
        }
        const ushort* Wk = Wpack + (size_t)ks * 128 * 32;
#pragma unroll
        for (int q = 0; q < 4; ++q) {
            union { uint4 u; bf16x8 v; } bv;
            bv.u = *reinterpret_cast<const uint4*>(
                Wk + (((nt0 + q) * 16 + mrow) * 32 + g * 8));
            acc[q] = __builtin_amdgcn_mfma_f32_16x16x32_bf16(av.v, bv.v, acc[q], 0, 0, 0);
        }
    }

    // ---- epilogue ----
#pragma unroll
    for (int q = 0; q < 4; ++q) {
        const int col = (nt0 + q) * 16 + mrow;
        const float bias = bias0[col] + bias1[col];
#pragma unroll
        for (int r = 0; r < 4; ++r) {
            const int row = b * BN + mt * 16 + g * 4 + r;
            if (row < N_NODES) {
                const float v = acc[q][r] + bias;
                if (act) outf[(size_t)row * D + col] = 1.0f / (1.0f + expf(-v));
                else     outb[(size_t)row * D + col] = (ushort)fp2bf_rn(v);
            }
        }
    }
}

// ---------------------------------------------------------------------------
extern "C" void kernel_launch(void* const* d_in, const int* in_sizes, int n_in,
                              void* d_out, int out_size, void* d_ws, size_t ws_size,
                              hipStream_t stream) {
    const float* x    = (const float*)d_in[0];
    const int*   ei_a = (const int*)d_in[2];
    const int*   ei_b = (const int*)d_in[3];
    const float* Wl   = (const float*)d_in[4];
    const float* bl   = (const float*)d_in[5];
    const float* Wr   = (const float*)d_in[6];
    float* out = (float*)d_out;

    // ---- workspace (~38.6 MB) ----
    ushort* featb = (ushort*)d_ws;                           // [N][128]
    ushort* feat2 = featb + (size_t)N_NODES * D;             // [N][128]
    uint* ebufA = (uint*)(feat2 + (size_t)N_NODES * D);      // NBUCK*CAP
    uint* ebufB = ebufA + (size_t)NBUCK * CAP;
    ushort* idxA = (ushort*)(ebufB + (size_t)NBUCK * CAP);   // NBUCK*CAP
    ushort* idxB = idxA + (size_t)NBUCK * CAP;
    int* pbegA = (int*)(idxB + (size_t)NBUCK * CAP);         // N
    int* pendA = pbegA + N_NODES;
    int* pbegB = pendA + N_NODES;
    int* pendB = pbegB + N_NODES;
    int* bcurA = pendB + N_NODES;                            // NBUCK
    int* bcurB = bcurA + NBUCK;
    ushort* Wpack = (ushort*)(((size_t)(bcurB + NBUCK) + 63) & ~(size_t)63);

    const int* srcA = ei_a;
    const int* dstA = ei_a + NE;
    const int* srcB = ei_b;
    const int* dstB = ei_b + NE;

    hipMemsetAsync(bcurA, 0, 2ull * NBUCK * sizeof(int), stream);
    build_kernel<<<2 * PBLK + F2B_BLKS + WPREP_BLKS, 256, 0, stream>>>(
        (const float4*)x, (uint2*)featb, Wl, Wr, Wpack,
        srcA, dstA, srcB, dstB, bcurA, bcurB, ebufA, ebufB);
    csrfill_kernel<<<2 * NBUCK, 256, 0, stream>>>(
        ebufA, bcurA, pbegA, pendA, idxA,
        ebufB, bcurB, pbegB, pendB, idxB);

    fused_kernel<<<NBUCK, 512, 0, stream>>>(
        (const uint4*)featb, pbegA, pendA, idxA, pbegB, pendB, idxB,
        Wpack, bl + 0 * D, bl + 1 * D, nullptr, feat2, 0);
    fused_kernel<<<NBUCK, 512, 0, stream>>>(
        (const uint4*)feat2, pbegA, pendA, idxA, pbegB, pendB, idxB,
        Wpack + (size_t)12 * 128 * 32, bl + 2 * D, bl + 3 * D, out, nullptr, 1);
}

// Round 9
// 203.214 us; speedup vs baseline: 13.4871x; 1.1366x over previous
//
#include <hip/hip_runtime.h>
#include <math.h>

#define N_NODES 50000
#define D 128
#define NE 800000
#define BN 64                  // nodes per bucket (dst >> 6)
#define NBUCK 782              // ceil(N_NODES / 64)
#define CAP 1280               // records per bucket (mean 1024, sigma 32 -> 8 sigma)
#define EPB 4096               // edges per partition block
#define PBLK 196               // ceil(NE / EPB)
#define F2B_BLKS 6250          // N*D/4 / 256
#define WPREP_BLKS 384         // 2*12*128*32 / 256
#define MPITCH 68              // uint pitch for LDS mean rows

typedef unsigned int uint;
typedef unsigned short ushort;

using bf16x8 = __attribute__((ext_vector_type(8))) short;
using f32x4  = __attribute__((ext_vector_type(4))) float;

// ---- bf16 helpers (bit-level, RN-even) ----
__device__ __forceinline__ float bflo(uint w) {
    union { uint u; float f; } c; c.u = w << 16; return c.f;
}
__device__ __forceinline__ float bfhi(uint w) {
    union { uint u; float f; } c; c.u = w & 0xffff0000u; return c.f;
}
__device__ __forceinline__ uint fp2bf_rn(float f) {
    union { float f; uint u; } c; c.f = f;
    return (c.u + 0x7fffu + ((c.u >> 16) & 1u)) >> 16;
}

// ---------------------------------------------------------------------------
// build: [0, 2*PBLK) edge partition into bucket record runs;
//        then x -> bf16; then W pre-pack.
// rec = src | (dst&63)<<17.  After this kernel bcur[b] = bucket record count.
// ---------------------------------------------------------------------------
__global__ __launch_bounds__(256) void build_kernel(
    const float4* __restrict__ x4, uint2* __restrict__ featb2,
    const float* __restrict__ Wl, const float* __restrict__ Wr,
    ushort* __restrict__ Wpack,
    const int* __restrict__ srcA, const int* __restrict__ dstA,
    const int* __restrict__ srcB, const int* __restrict__ dstB,
    int* __restrict__ bcurA, int* __restrict__ bcurB,
    uint* __restrict__ ebufA, uint* __restrict__ ebufB) {
    const int blk = blockIdx.x;
    const int t   = threadIdx.x;
    if (blk < 2 * PBLK) {
        __shared__ int h[NBUCK];
        __shared__ int base[NBUCK];
        const int typ = blk >= PBLK;
        const int* src = typ ? srcB : srcA;
        const int* dst = typ ? dstB : dstA;
        int* bc        = typ ? bcurB : bcurA;
        uint* ebuf     = typ ? ebufB : ebufA;
        const int e0 = (blk - (typ ? PBLK : 0)) * EPB;
        for (int j = t; j < NBUCK; j += 256) h[j] = 0;
        __syncthreads();
#pragma unroll
        for (int i = 0; i < EPB / 256; ++i) {
            const int e = e0 + t + i * 256;
            if (e < NE) atomicAdd(&h[dst[e] >> 6], 1);
        }
        __syncthreads();
        for (int j = t; j < NBUCK; j += 256) {
            const int c = h[j];
            base[j] = c ? atomicAdd(&bc[j], c) : 0;
            h[j] = 0;                    // reuse as local cursor
        }
        __syncthreads();
#pragma unroll
        for (int i = 0; i < EPB / 256; ++i) {
            const int e = e0 + t + i * 256;
            if (e < NE) {
                const int d  = dst[e];
                const int bk = d >> 6;
                const int pos = atomicAdd(&h[bk], 1);
                const int off = base[bk] + pos;
                if (off < CAP)
                    ebuf[(size_t)bk * CAP + off] = (uint)src[e] | ((uint)(d & 63) << 17);
            }
        }
    } else if (blk < 2 * PBLK + F2B_BLKS) {
        const int i = (blk - 2 * PBLK) * 256 + t;
        float4 v = x4[i];
        uint2 o;
        o.x = fp2bf_rn(v.x) | (fp2bf_rn(v.y) << 16);
        o.y = fp2bf_rn(v.z) | (fp2bf_rn(v.w) << 16);
        featb2[i] = o;
    } else {
        const int i   = (blk - 2 * PBLK - F2B_BLKS) * 256 + t;  // [2][12][128][32]
        const int l   = i / 49152;
        const int rem = i % 49152;
        const int ks  = rem / 4096;
        const int n   = (rem % 4096) / 32;
        const int kk  = rem % 32;
        const int r   = ks * 32 + kk;
        float v;
        if (r < 128)       v = Wl[(((size_t)l * 2 + 0) * 128 + r) * 128 + n];
        else if (r < 256)  v = Wl[(((size_t)l * 2 + 1) * 128 + (r - 128)) * 128 + n];
        else               v = Wr[(((size_t)l * 2 + 0) * 128 + (r - 256)) * 128 + n]
                             + Wr[(((size_t)l * 2 + 1) * 128 + (r - 256)) * 128 + n];
        Wpack[i] = (ushort)fp2bf_rn(v);
    }
}

// ---------------------------------------------------------------------------
// fused: per 64-node bucket:
//  (1) LDS sort of the bucket's records into per-node lists (replaces csrfill)
//  (2) register-accumulated mean gather (both types) -> LDS bf16 means
//  (3) in-kernel 64x128 MFMA GEMM over K=384 = [meanA|meanB|self]
//      out[i,:] = act( meanA@W0 + meanB@W1 + self@(Wr0+Wr1) + b0+b1 )
// 1024 threads = 16 waves; 64 gather clusters x 16 lanes;
// GEMM: wave w -> Mtile w>>2, Ntile pair (w&3)*2.
// ---------------------------------------------------------------------------
__global__ __launch_bounds__(1024, 8) void fused_kernel(
    const uint4* __restrict__ feat,      // layer input, bf16 [N][16]
    const uint* __restrict__ ebufA, const uint* __restrict__ ebufB,
    const int* __restrict__ bcntA, const int* __restrict__ bcntB,
    const ushort* __restrict__ Wpack,    // [12][128][32] bf16 for this layer
    const float* __restrict__ bias0, const float* __restrict__ bias1,
    float* __restrict__ outf, ushort* __restrict__ outb, int act) {

    __shared__ uint   mlds[2 * BN * MPITCH];   // bf16 means  (34816 B)
    __shared__ ushort lidx[2][CAP];            // per-node src lists (5120 B)
    __shared__ int    cnt[128], ex[128], cur[128];

    const int b = blockIdx.x;
    const int t = threadIdx.x;

    // ---- (1) in-LDS per-node sort of bucket records ----
    if (t < 128) cnt[t] = 0;
    __syncthreads();
    int countA = bcntA[b]; if (countA > CAP) countA = CAP;
    int countB = bcntB[b]; if (countB > CAP) countB = CAP;
    const uint* ebA = ebufA + (size_t)b * CAP;
    const uint* ebB = ebufB + (size_t)b * CAP;
    for (int e = t; e < countA; e += 1024) atomicAdd(&cnt[ebA[e] >> 17], 1);
    for (int e = t; e < countB; e += 1024) atomicAdd(&cnt[64 + (ebB[e] >> 17)], 1);
    __syncthreads();
    if (t < 128) ex[t] = cnt[t];
    __syncthreads();
    // two independent 64-wide Hillis-Steele scans (threads 0-63 and 64-127)
    for (int off = 1; off < 64; off <<= 1) {
        int v = 0;
        if (t < 128 && (t & 63) >= off) v = ex[t - off];
        __syncthreads();
        if (t < 128 && (t & 63) >= off) ex[t] += v;
        __syncthreads();
    }
    if (t < 128) { ex[t] -= cnt[t]; cur[t] = ex[t]; }   // exclusive base
    __syncthreads();
    for (int e = t; e < countA; e += 1024) {
        const uint rec = ebA[e];
        const int p = atomicAdd(&cur[rec >> 17], 1);
        lidx[0][p] = (ushort)(rec & 0x1FFFFu);
    }
    for (int e = t; e < countB; e += 1024) {
        const uint rec = ebB[e];
        const int p = atomicAdd(&cur[64 + (rec >> 17)], 1);
        lidx[1][p] = (ushort)(rec & 0x1FFFFu);
    }
    __syncthreads();

    // ---- (2) gather phase: 64 clusters x 16 lanes, register accumulation ----
    const int cl = t >> 4, ln = t & 15;
#pragma unroll
    for (int typ = 0; typ < 2; ++typ) {
        const int beg = ex[typ * 64 + cl];
        const int fin = beg + cnt[typ * 64 + cl];
        const ushort* lx = lidx[typ];
        float a[8] = {0.f,0.f,0.f,0.f,0.f,0.f,0.f,0.f};
#define ACC(v) { a[0]+=bflo(v.x); a[1]+=bfhi(v.x); a[2]+=bflo(v.y); a[3]+=bfhi(v.y); \
                 a[4]+=bflo(v.z); a[5]+=bfhi(v.z); a[6]+=bflo(v.w); a[7]+=bfhi(v.w); }
        int e = beg;
        for (; e + 4 <= fin; e += 4) {
            uint4 v0 = feat[(size_t)lx[e]     * 16 + ln];
            uint4 v1 = feat[(size_t)lx[e + 1] * 16 + ln];
            uint4 v2 = feat[(size_t)lx[e + 2] * 16 + ln];
            uint4 v3 = feat[(size_t)lx[e + 3] * 16 + ln];
            ACC(v0); ACC(v1); ACC(v2); ACC(v3);
        }
        for (; e < fin; ++e) {
            uint4 v0 = feat[(size_t)lx[e] * 16 + ln];
            ACC(v0);
        }
#undef ACC
        const float invd = 1.0f / fmaxf((float)(fin - beg), 1.0f);
        uint4 o;
        o.x = fp2bf_rn(a[0] * invd) | (fp2bf_rn(a[1] * invd) << 16);
        o.y = fp2bf_rn(a[2] * invd) | (fp2bf_rn(a[3] * invd) << 16);
        o.z = fp2bf_rn(a[4] * invd) | (fp2bf_rn(a[5] * invd) << 16);
        o.w = fp2bf_rn(a[6] * invd) | (fp2bf_rn(a[7] * invd) << 16);
        *reinterpret_cast<uint4*>(&mlds[(typ * BN + cl) * MPITCH + ln * 4]) = o;
    }
    __syncthreads();

    // ---- (3) GEMM phase: 64 rows x 128 cols, K = 12 x 32, 16 waves ----
    const int wid = t >> 6, wl = t & 63;
    const int mrow = wl & 15, g = wl >> 4;
    const int mt   = wid >> 2;             // 0..3
    const int ntp  = (wid & 3) * 2;        // 0,2,4,6
    const int arow = mt * 16 + mrow;       // 0..63

    f32x4 acc0 = (f32x4){0.f, 0.f, 0.f, 0.f};
    f32x4 acc1 = (f32x4){0.f, 0.f, 0.f, 0.f};
#pragma unroll
    for (int ks = 0; ks < 12; ++ks) {
        union { uint4 u; bf16x8 v; } av;
        if (ks < 8) {
            av.u = *reinterpret_cast<const uint4*>(
                &mlds[((ks >> 2) * BN + arow) * MPITCH + (ks & 3) * 16 + g * 4]);
        } else {
            int srow = b * BN + arow;
            if (srow >= N_NODES) srow = N_NODES - 1;
            av.u = feat[(size_t)srow * 16 + (ks & 3) * 4 + g];
        }
        const ushort* Wk = Wpack + (size_t)ks * 128 * 32;
        union { uint4 u; bf16x8 v; } bv0, bv1;
        bv0.u = *reinterpret_cast<const uint4*>(Wk + ((ntp * 16 + mrow) * 32 + g * 8));
        bv1.u = *reinterpret_cast<const uint4*>(Wk + (((ntp + 1) * 16 + mrow) * 32 + g * 8));
        acc0 = __builtin_amdgcn_mfma_f32_16x16x32_bf16(av.v, bv0.v, acc0, 0, 0, 0);
        acc1 = __builtin_amdgcn_mfma_f32_16x16x32_bf16(av.v, bv1.v, acc1, 0, 0, 0);
    }

    // ---- epilogue ----
#pragma unroll
    for (int q = 0; q < 2; ++q) {
        const f32x4 av = q ? acc1 : acc0;
        const int col = (ntp + q) * 16 + mrow;
        const float bias = bias0[col] + bias1[col];
#pragma unroll
        for (int r = 0; r < 4; ++r) {
            const int row = b * BN + mt * 16 + g * 4 + r;
            if (row < N_NODES) {
                const float v = av[r] + bias;
                if (act) outf[(size_t)row * D + col] = 1.0f / (1.0f + expf(-v));
                else     outb[(size_t)row * D + col] = (ushort)fp2bf_rn(v);
            }
        }
    }
}

// ---------------------------------------------------------------------------
extern "C" void kernel_launch(void* const* d_in, const int* in_sizes, int n_in,
                              void* d_out, int out_size, void* d_ws, size_t ws_size,
                              hipStream_t stream) {
    const float* x    = (const float*)d_in[0];
    const int*   ei_a = (const int*)d_in[2];
    const int*   ei_b = (const int*)d_in[3];
    const float* Wl   = (const float*)d_in[4];
    const float* bl   = (const float*)d_in[5];
    const float* Wr   = (const float*)d_in[6];
    float* out = (float*)d_out;

    // ---- workspace (~33.8 MB) ----
    ushort* featb = (ushort*)d_ws;                           // [N][128]
    ushort* feat2 = featb + (size_t)N_NODES * D;             // [N][128]
    uint* ebufA = (uint*)(feat2 + (size_t)N_NODES * D);      // NBUCK*CAP
    uint* ebufB = ebufA + (size_t)NBUCK * CAP;
    int* bcurA  = (int*)(ebufB + (size_t)NBUCK * CAP);       // NBUCK
    int* bcurB  = bcurA + NBUCK;
    ushort* Wpack = (ushort*)(((size_t)(bcurB + NBUCK) + 63) & ~(size_t)63);

    const int* srcA = ei_a;
    const int* dstA = ei_a + NE;
    const int* srcB = ei_b;
    const int* dstB = ei_b + NE;

    hipMemsetAsync(bcurA, 0, 2ull * NBUCK * sizeof(int), stream);
    build_kernel<<<2 * PBLK + F2B_BLKS + WPREP_BLKS, 256, 0, stream>>>(
        (const float4*)x, (uint2*)featb, Wl, Wr, Wpack,
        srcA, dstA, srcB, dstB, bcurA, bcurB, ebufA, ebufB);

    fused_kernel<<<NBUCK, 1024, 0, stream>>>(
        (const uint4*)featb, ebufA, ebufB, bcurA, bcurB,
        Wpack, bl + 0 * D, bl + 1 * D, nullptr, feat2, 0);
    fused_kernel<<<NBUCK, 1024, 0, stream>>>(
        (const uint4*)feat2, ebufA, ebufB, bcurA, bcurB,
        Wpack + (size_t)12 * 128 * 32, bl + 2 * D, bl + 3 * D, out, nullptr, 1);
}